// Round 8
// baseline (1748.819 us; speedup 1.0000x reference)
//
#include <hip/hip_runtime.h>
#include <math.h>

// Problem constants
#define DIMS   6
#define NGEO   20
#define NPHI   27
#define NEXPERT 540
#define MPTS   256
#define NTEST  1024
#define NMAT   560          // experts + baselines
#define JIT    1e-4f
#define USTRIDE 33280       // packed padded upper-triangular floats per matrix
#define PSW    260          // LDS panel row stride
#define L2E    1.44269504088896340736f

// Row j of U (cols j..255) starts at uoff(j); each row padded to 4-float multiple.
__device__ __forceinline__ int uoff(int j){
    int m = j >> 2, r = j & 3;
    return 1024*m - 8*m*(m-1) + r*(256 - 4*m);
}

// ---------------------------------------------------------------------------
// Kernel 0: zero the needed-mask (ws is poisoned 0xAA before each launch)
// ---------------------------------------------------------------------------
__global__ __launch_bounds__(1024)
void zero_kernel(int* __restrict__ needed){
    int t = threadIdx.x;
    if (t < NMAT) needed[t] = 0;
}

// ---------------------------------------------------------------------------
// Kernel 1: 2-level GMM hard routing (fp64 to match np reference argmax)
//           + mark routed non-null experts as needed
// ---------------------------------------------------------------------------
__global__ __launch_bounds__(256)
void route_kernel(const float* __restrict__ Xt, const float* __restrict__ sm,
                  const float* __restrict__ ss,
                  const float* __restrict__ gm, const float* __restrict__ glv,
                  const float* __restrict__ glw,
                  const float* __restrict__ pm, const float* __restrict__ plv,
                  const float* __restrict__ plw,
                  const int* __restrict__ nullmask,
                  int* __restrict__ e_idx, int* __restrict__ g_idx,
                  int* __restrict__ needed)
{
    int n = blockIdx.x*256 + threadIdx.x;
    if (n >= NTEST) return;
    double xs[DIMS];
    #pragma unroll
    for (int d=0; d<DIMS; d++)
        xs[d] = ((double)Xt[n*DIMS+d] - (double)sm[d]) / (double)ss[d];
    const double cst = (double)DIMS * 1.8378770664093453;  // D*log(2*pi)

    int bg = 0; double best = -1e300;
    for (int j=0; j<NGEO; j++){
        double s = 0.0;
        #pragma unroll
        for (int d=0; d<DIMS; d++){
            double lv = (double)glv[j*DIMS+d];
            double df = xs[d] - (double)gm[j*DIMS+d];
            s += lv + df*df*exp(-lv);
        }
        double lp = (double)glw[j] - 0.5*(s + cst);
        if (lp > best){ best = lp; bg = j; }
    }
    int bk = 0; best = -1e300;
    for (int k=0; k<NPHI; k++){
        double s = 0.0;
        int o = (bg*NPHI + k)*DIMS;
        #pragma unroll
        for (int d=0; d<DIMS; d++){
            double lv = (double)plv[o+d];
            double df = xs[d] - (double)pm[o+d];
            s += lv + df*df*exp(-lv);
        }
        double lp = (double)plw[bg*NPHI+k] - 0.5*(s + cst);
        if (lp > best){ best = lp; bk = k; }
    }
    int e = bg*NPHI + bk;
    e_idx[n] = e;
    g_idx[n] = bg;
    if (nullmask[e] != 0) needed[e] = 1;   // benign race: same value
}

// ---------------------------------------------------------------------------
// Kernel 1b: compact needed matrices into a worklist (single block)
// ---------------------------------------------------------------------------
__global__ __launch_bounds__(1024)
void compact_kernel(const int* __restrict__ needed,
                    int* __restrict__ list, int* __restrict__ cnt)
{
    __shared__ int s[1024];
    int t = threadIdx.x;
    int nd = 0;
    if (t < NEXPERT) nd = needed[t];
    else if (t < NMAT) nd = 1;             // baselines always needed
    s[t] = nd;
    __syncthreads();
    // Hillis-Steele inclusive scan
    for (int off=1; off<1024; off<<=1){
        int v = (t >= off) ? s[t-off] : 0;
        __syncthreads();
        s[t] += v;
        __syncthreads();
    }
    if (nd) list[s[t]-1] = t;
    if (t == NMAT-1) cnt[0] = s[t];
}

// ---------------------------------------------------------------------------
// Kernel 2: right-looking blocked Cholesky (R2 structure revived), worklist-
// indexed. With ~95 compacted blocks the 133 KB/matrix working set is
// L2-resident (12 blocks/XCD x 133 KB ~= 1.6 MB << 4 MB L2) so the syrk's
// global churn is L2-hot, and its 8x8 register tiles are VALU-bound.
// No min-waves bound: at 1 block/CU occupancy is irrelevant; let the
// allocator keep the 8x8 accumulators in registers.
// ---------------------------------------------------------------------------
__global__ __launch_bounds__(256)
void chol_kernel(const float* __restrict__ X_exp, const float* __restrict__ Y_exp,
                 const float* __restrict__ X_base, const float* __restrict__ Y_base,
                 const float* __restrict__ lls_e, const float* __restrict__ los_e,
                 const float* __restrict__ lno_e,
                 const float* __restrict__ lls_b, const float* __restrict__ los_b,
                 const float* __restrict__ lno_b,
                 const int* __restrict__ list, const int* __restrict__ cnt,
                 float* __restrict__ Uws, float* __restrict__ Vws)
{
    if (blockIdx.x >= cnt[0]) return;      // early-exit: not needed this run
    int mat = list[blockIdx.x];

    __shared__ __align__(16) float Ps[32*PSW];   // panel rows (base-relative cols)
    __shared__ float Dl[32*36];                  // D = diag block of L, row-major
    __shared__ float Dinv[32];                   // 1/diag(L)

    int t = threadIdx.x;
    const float *Xtr, *Ytr;
    float lls, los, lno;
    if (mat < NEXPERT){
        Xtr = X_exp + mat*(MPTS*DIMS); Ytr = Y_exp + mat*MPTS;
        lls = lls_e[mat]; los = los_e[mat]; lno = lno_e[mat];
    } else {
        int g = mat - NEXPERT;
        Xtr = X_base + g*(MPTS*DIMS); Ytr = Y_base + g*MPTS;
        lls = lls_b[g]; los = los_b[g]; lno = lno_b[g];
    }
    float ls2 = expf(2.f*lls);
    float os  = expf(los);
    float nv  = expf(lno) + JIT;
    float c1  = -0.5f*L2E/ls2;
    float* Ug = Uws + (size_t)mat*USTRIDE;
    float* Xs = Ps;                    // alias: build phase only (2048 floats)

    // stage X into LDS (padded stride 8; slots 6,7 never read)
    for (int i=t; i<MPTS*DIMS; i+=256){ int r=i/DIMS, d=i-r*DIMS; Xs[r*8+d]=Xtr[i]; }
    __syncthreads();

    // build K: thread t builds row t of U (cols t..255)
    {
        float x0=Xs[t*8+0], x1=Xs[t*8+1], x2=Xs[t*8+2];
        float x3=Xs[t*8+3], x4=Xs[t*8+4], x5=Xs[t*8+5];
        int ro = uoff(t), len = 256 - t;
        for (int ii=0; ii<len; ii++){
            int i = t + ii;
            float4 a  = *(const float4*)&Xs[i*8];
            float2 b2 = *(const float2*)&Xs[i*8+4];
            float d0=x0-a.x, d1=x1-a.y, d2=x2-a.z, d3=x3-a.w, d4=x4-b2.x, d5=x5-b2.y;
            float dd = d0*d0+d1*d1+d2*d2+d3*d3+d4*d4+d5*d5;
            float u = os*exp2f(c1*dd);
            if (ii==0) u += nv;
            Ug[ro+ii] = u;
        }
        int lp = (len+3)&~3;
        for (int ii=len; ii<lp; ii++) Ug[ro+ii] = 0.f;
    }
    __syncthreads();   // also protects Xs before Ps reuse

    for (int s=0; s<8; s++){
        int base = 32*s;
        int nt = 224 - base;           // trailing size
        // ---- 1. load panel rows (global -> LDS), coalesced per row ----
        #pragma unroll
        for (int c=0; c<32; c++){
            int j = base + c;
            int len = 256 - j;
            if (t < len) Ps[c*PSW + c + t] = Ug[uoff(j) + t];
        }
        __syncthreads();
        // ---- 2. diag 32x32 factor by lanes 0..31 of wave 0 (shfl, no barriers)
        if (t < 32){
            int l = t;
            float r[32];
            #pragma unroll
            for (int k=0; k<32; k++) r[k] = (k <= l) ? Ps[k*PSW + l] : 0.f;
            float myinv = 1.f;
            #pragma unroll
            for (int c=0; c<32; c++){
                float pivsq = __shfl(r[c], c);
                float inv = rsqrtf(pivsq);
                r[c] *= inv;
                if (l == c) myinv = inv;
                #pragma unroll
                for (int k=c+1; k<32; k++) r[k] -= r[c]*__shfl(r[c], k);
            }
            Dinv[l] = myinv;
            #pragma unroll
            for (int j=0; j<32; j++){
                if (j <= l){ Dl[l*36 + j] = r[j]; Ps[j*PSW + l] = r[j]; }
            }
        }
        __syncthreads();
        // ---- 3. trsm: thread-parallel, 2 columns per thread, D via LDS broadcast
        {
            int nt2 = nt >> 1;
            if (t < nt2){
                int it0 = 32 + t, it1 = 32 + nt2 + t;
                float x0[32], x1[32];
                #pragma unroll
                for (int k=0; k<32; k++){
                    x0[k] = Ps[k*PSW + it0];
                    x1[k] = Ps[k*PSW + it1];
                }
                #pragma unroll
                for (int c=0; c<32; c++){
                    float dinv = Dinv[c];
                    float a0 = x0[c]*dinv, a1 = x1[c]*dinv;
                    x0[c] = a0; x1[c] = a1;
                    #pragma unroll
                    for (int k=c+1; k<32; k++){
                        float dkc = Dl[k*36 + c];     // broadcast read
                        x0[k] -= dkc*a0;
                        x1[k] -= dkc*a1;
                    }
                }
                #pragma unroll
                for (int k=0; k<32; k++){
                    Ps[k*PSW + it0] = x0[k];
                    Ps[k*PSW + it1] = x1[k];
                }
            }
        }
        __syncthreads();
        // ---- 4a. write panel back to global (coalesced rows, zero pads) ----
        #pragma unroll
        for (int c=0; c<32; c++){
            int j = base + c;
            int len = 256 - j, lp = (259 - j) & ~3;
            if (t < lp) Ug[uoff(j) + t] = (t < len) ? Ps[c*PSW + c + t] : 0.f;
        }
        // ---- 4b. syrk trailing update: 8x8 register tiles, panel from LDS ----
        {
            int tb = base + 32;
            int ntile = nt >> 3;
            int tri = ntile*(ntile+1)/2;
            for (int tp = t; tp < tri; tp += 256){
                int ti = (int)((sqrtf(8.f*(float)tp + 1.f) - 1.f)*0.5f);
                while ((ti+1)*(ti+2)/2 <= tp) ti++;
                while (ti*(ti+1)/2 > tp) ti--;
                int tj = tp - ti*(ti+1)/2;
                int I0 = tb + ti*8, K0 = tb + tj*8;
                float acc[8][8];
                int roK[8];
                #pragma unroll
                for (int kk=0; kk<8; kk++) roK[kk] = uoff(K0+kk);
                #pragma unroll
                for (int kk=0; kk<8; kk++){
                    int kr = K0+kk;
                    #pragma unroll
                    for (int ii=0; ii<8; ii++){
                        int ic = I0+ii;
                        acc[kk][ii] = (ic >= kr) ? Ug[roK[kk] + ic - kr] : 0.f;
                    }
                }
                int i0r = I0 - base, k0r = K0 - base;
                #pragma unroll
                for (int c=0; c<32; c++){
                    float4 a0 = *(const float4*)&Ps[c*PSW + i0r];
                    float4 a1 = *(const float4*)&Ps[c*PSW + i0r + 4];
                    float4 b0 = *(const float4*)&Ps[c*PSW + k0r];
                    float4 b1 = *(const float4*)&Ps[c*PSW + k0r + 4];
                    float av[8] = {a0.x,a0.y,a0.z,a0.w,a1.x,a1.y,a1.z,a1.w};
                    float bv[8] = {b0.x,b0.y,b0.z,b0.w,b1.x,b1.y,b1.z,b1.w};
                    #pragma unroll
                    for (int kk=0; kk<8; kk++)
                        #pragma unroll
                        for (int ii=0; ii<8; ii++)
                            acc[kk][ii] -= bv[kk]*av[ii];
                }
                #pragma unroll
                for (int kk=0; kk<8; kk++){
                    int kr = K0+kk;
                    #pragma unroll
                    for (int ii=0; ii<8; ii++){
                        int ic = I0+ii;
                        if (ic >= kr) Ug[roK[kk] + ic - kr] = acc[kk][ii];
                    }
                }
            }
        }
        __syncthreads();
    }

    // v = L^-1 y  (forward solve, wave 0 only; L columns = U rows, coalesced)
    if (t < 64){
        int l = t;
        float z[4], rd[4];
        #pragma unroll
        for (int q=0; q<4; q++){
            z[q]  = Ytr[64*q + l];
            rd[q] = 1.f/Ug[uoff(64*q + l)];
        }
        int offj = 0;
        #pragma unroll
        for (int q=0; q<4; q++){
            for (int j2=0; j2<64; j2++){
                int j = 64*q + j2;
                float zf = __shfl(z[q], j2) * __shfl(rd[q], j2);
                if (l == j2) z[q] = zf;
                #pragma unroll
                for (int r=q; r<4; r++){
                    int dd = 64*(r-q) + (l - j2);
                    int dc = dd > 0 ? dd : 0;
                    float uv = Ug[offj + dc];
                    if (dd > 0) z[r] -= uv*zf;
                }
                offj += (259-j)&~3;
            }
        }
        #pragma unroll
        for (int q=0; q<4; q++) Vws[mat*256 + 64*q + l] = z[q];
    }
}

// ---------------------------------------------------------------------------
// Kernel 3: per-point prediction (one wave per (point, side)) + rBCM combine.
// Null experts skip the solve (var<-prior => beta_e=0, no poisoned-U reads).
// ---------------------------------------------------------------------------
__global__ __launch_bounds__(256)
void predict_kernel(const float* __restrict__ Xt,
                    const float* __restrict__ X_exp, const float* __restrict__ X_base,
                    const float* __restrict__ lls_e, const float* __restrict__ los_e,
                    const float* __restrict__ lno_e,
                    const float* __restrict__ lls_b, const float* __restrict__ los_b,
                    const float* __restrict__ lno_b,
                    const int* __restrict__ nullmask,
                    const float* __restrict__ Uws, const float* __restrict__ Vws,
                    const int* __restrict__ e_idx, const int* __restrict__ g_idx,
                    float* __restrict__ out)
{
    __shared__ float res[4][4];   // per local wave: mu, var, prior
    int lw = threadIdx.x >> 6, l = threadIdx.x & 63;
    int wt = blockIdx.x*4 + lw, n = wt >> 1, side = wt & 1;

    int bidx; const float* Xtr; float lls, los, lno;
    bool isnull = false;
    if (side == 0){
        int ee = e_idx[n]; bidx = ee; Xtr = X_exp + ee*(MPTS*DIMS);
        lls = lls_e[ee]; los = los_e[ee]; lno = lno_e[ee];
        isnull = (nullmask[ee] == 0);
    } else {
        int g = g_idx[n]; bidx = NEXPERT + g; Xtr = X_base + g*(MPTS*DIMS);
        lls = lls_b[g]; los = los_b[g]; lno = lno_b[g];
    }
    float ls2 = expf(2.f*lls), os = expf(los), nv = expf(lno) + JIT;
    float c1 = -0.5f*L2E/ls2;

    if (!isnull){   // wave-uniform branch
        float xt[DIMS];
        #pragma unroll
        for (int d=0; d<DIMS; d++) xt[d] = Xt[n*DIMS + d];

        const float* Ug = Uws + (size_t)bidx*USTRIDE;
        const float* vv = Vws + bidx*256;

        // k* into registers (rows 64q+l), plus diag reciprocals
        float z[4], rd[4];
        #pragma unroll
        for (int q=0; q<4; q++){
            int m = 64*q + l;
            float d2 = 0.f;
            #pragma unroll
            for (int d=0; d<DIMS; d++){ float df = xt[d]-Xtr[m*DIMS+d]; d2 += df*df; }
            z[q]  = os*exp2f(c1*d2);
            rd[q] = 1.f/Ug[uoff(m)];
        }
        // w = L^-1 k*  (forward solve; L columns = U rows, coalesced loads)
        int offj = 0;
        #pragma unroll
        for (int q=0; q<4; q++){
            #pragma unroll 4
            for (int j2=0; j2<64; j2++){
                int j = 64*q + j2;
                float zf = __shfl(z[q], j2) * __shfl(rd[q], j2);
                if (l == j2) z[q] = zf;
                #pragma unroll
                for (int r=q; r<4; r++){
                    int dd = 64*(r-q) + (l - j2);
                    int dc = dd > 0 ? dd : 0;
                    float uv = Ug[offj + dc];
                    if (dd > 0) z[r] -= uv*zf;
                }
                offj += (259-j)&~3;
            }
        }
        // q = w.w ; mu = w.v
        float qq = 0.f, mu = 0.f;
        #pragma unroll
        for (int q=0; q<4; q++){ qq += z[q]*z[q]; mu += z[q]*vv[64*q + l]; }
        #pragma unroll
        for (int o=32; o>0; o>>=1){ qq += __shfl_xor(qq, o); mu += __shfl_xor(mu, o); }
        if (l == 0){
            res[lw][0] = mu;
            res[lw][1] = fmaxf(os - qq, JIT) + nv;   // predictive var incl noise
            res[lw][2] = os + nv;                    // prior
        }
    } else {
        if (l == 0){
            res[lw][0] = 0.f;
            res[lw][1] = os + nv;    // var = prior -> beta_e = 0, no NaN
            res[lw][2] = os + nv;
        }
    }
    __syncthreads();
    if (threadIdx.x < 2){
        int pp = threadIdx.x, n2 = blockIdx.x*2 + pp;
        float mu_e = res[2*pp][0],   var_e = res[2*pp][1],   pr_e = res[2*pp][2];
        float mu_b = res[2*pp+1][0], var_b = res[2*pp+1][1], pr_b = res[2*pp+1][2];
        int ee = e_idx[n2];
        float be = (nullmask[ee] == 0) ? 0.f
                 : fmaxf(0.5f*(logf(pr_e) - logf(var_e)), 0.f);
        float bb = fmaxf(0.5f*(logf(pr_b) - logf(var_b)), 0.f);
        float prec = be/var_e + bb/var_b + (1.f - be - bb)/pr_b;
        prec = fmaxf(prec, 1e-6f);
        out[n2]        = (be*mu_e/var_e + bb*mu_b/var_b)/prec;
        out[NTEST + n2] = 1.f/prec;
    }
}

// ---------------------------------------------------------------------------
extern "C" void kernel_launch(void* const* d_in, const int* in_sizes, int n_in,
                              void* d_out, int out_size, void* d_ws, size_t ws_size,
                              hipStream_t stream)
{
    const float* X_test  = (const float*)d_in[0];
    const float* X_exp   = (const float*)d_in[1];
    const float* Y_exp   = (const float*)d_in[2];
    const float* X_base  = (const float*)d_in[3];
    const float* Y_base  = (const float*)d_in[4];
    const float* lls_e   = (const float*)d_in[5];
    const float* los_e   = (const float*)d_in[6];
    const float* lno_e   = (const float*)d_in[7];
    const float* lls_b   = (const float*)d_in[8];
    const float* los_b   = (const float*)d_in[9];
    const float* lno_b   = (const float*)d_in[10];
    const float* sm      = (const float*)d_in[11];
    const float* ss      = (const float*)d_in[12];
    const float* gm      = (const float*)d_in[13];
    const float* glv     = (const float*)d_in[14];
    const float* glw     = (const float*)d_in[15];
    const float* pm      = (const float*)d_in[16];
    const float* plv     = (const float*)d_in[17];
    const float* plw     = (const float*)d_in[18];
    const int*   nmask   = (const int*)d_in[19];

    float* Uws = (float*)d_ws;                       // NMAT*USTRIDE floats (74.5 MB)
    float* Vws = Uws + (size_t)NMAT*USTRIDE;         // NMAT*256 floats
    int*   e_idx  = (int*)(Vws + (size_t)NMAT*256);  // NTEST
    int*   g_idx  = e_idx + NTEST;                   // NTEST
    int*   needed = g_idx + NTEST;                   // NMAT
    int*   list   = needed + NMAT;                   // NMAT
    int*   cnt    = list + NMAT;                     // 1
    float* out = (float*)d_out;

    zero_kernel<<<dim3(1), dim3(1024), 0, stream>>>(needed);
    route_kernel<<<dim3(NTEST/256), dim3(256), 0, stream>>>(
        X_test, sm, ss, gm, glv, glw, pm, plv, plw, nmask, e_idx, g_idx, needed);
    compact_kernel<<<dim3(1), dim3(1024), 0, stream>>>(needed, list, cnt);
    chol_kernel<<<dim3(NMAT), dim3(256), 0, stream>>>(
        X_exp, Y_exp, X_base, Y_base,
        lls_e, los_e, lno_e, lls_b, los_b, lno_b, list, cnt, Uws, Vws);
    predict_kernel<<<dim3(NTEST/2), dim3(256), 0, stream>>>(
        X_test, X_exp, X_base,
        lls_e, los_e, lno_e, lls_b, los_b, lno_b,
        nmask, Uws, Vws, e_idx, g_idx, out);
}

// Round 9
// 483.837 us; speedup vs baseline: 3.6145x; 3.6145x over previous
//
#include <hip/hip_runtime.h>
#include <math.h>

// Problem constants
#define DIMS   6
#define NGEO   20
#define NPHI   27
#define NEXPERT 540
#define MPTS   256
#define NTEST  1024
#define NMAT   560          // experts + baselines
#define JIT    1e-4f
#define USTRIDE 33280       // packed padded upper-triangular floats per matrix
#define L2E    1.44269504088896340736f

// Row j of U (cols j..255) starts at uoff(j); each row padded to 4-float multiple.
__device__ __forceinline__ int uoff(int j){
    int m = j >> 2, r = j & 3;
    return 1024*m - 8*m*(m-1) + r*(256 - 4*m);
}

// ---------------------------------------------------------------------------
// Kernel 0: zero the needed-mask (ws is poisoned 0xAA before each launch)
// ---------------------------------------------------------------------------
__global__ __launch_bounds__(1024)
void zero_kernel(int* __restrict__ needed){
    int t = threadIdx.x;
    if (t < NMAT) needed[t] = 0;
}

// ---------------------------------------------------------------------------
// Kernel 1: 2-level GMM hard routing (fp64 to match np reference argmax)
//           + mark routed non-null experts as needed
// ---------------------------------------------------------------------------
__global__ __launch_bounds__(256)
void route_kernel(const float* __restrict__ Xt, const float* __restrict__ sm,
                  const float* __restrict__ ss,
                  const float* __restrict__ gm, const float* __restrict__ glv,
                  const float* __restrict__ glw,
                  const float* __restrict__ pm, const float* __restrict__ plv,
                  const float* __restrict__ plw,
                  const int* __restrict__ nullmask,
                  int* __restrict__ e_idx, int* __restrict__ g_idx,
                  int* __restrict__ needed)
{
    int n = blockIdx.x*256 + threadIdx.x;
    if (n >= NTEST) return;
    double xs[DIMS];
    #pragma unroll
    for (int d=0; d<DIMS; d++)
        xs[d] = ((double)Xt[n*DIMS+d] - (double)sm[d]) / (double)ss[d];
    const double cst = (double)DIMS * 1.8378770664093453;  // D*log(2*pi)

    int bg = 0; double best = -1e300;
    for (int j=0; j<NGEO; j++){
        double s = 0.0;
        #pragma unroll
        for (int d=0; d<DIMS; d++){
            double lv = (double)glv[j*DIMS+d];
            double df = xs[d] - (double)gm[j*DIMS+d];
            s += lv + df*df*exp(-lv);
        }
        double lp = (double)glw[j] - 0.5*(s + cst);
        if (lp > best){ best = lp; bg = j; }
    }
    int bk = 0; best = -1e300;
    for (int k=0; k<NPHI; k++){
        double s = 0.0;
        int o = (bg*NPHI + k)*DIMS;
        #pragma unroll
        for (int d=0; d<DIMS; d++){
            double lv = (double)plv[o+d];
            double df = xs[d] - (double)pm[o+d];
            s += lv + df*df*exp(-lv);
        }
        double lp = (double)plw[bg*NPHI+k] - 0.5*(s + cst);
        if (lp > best){ best = lp; bk = k; }
    }
    int e = bg*NPHI + bk;
    e_idx[n] = e;
    g_idx[n] = bg;
    if (nullmask[e] != 0) needed[e] = 1;   // benign race: same value
}

// ---------------------------------------------------------------------------
// Kernel 1b: compact needed matrices into a worklist (single block)
// ---------------------------------------------------------------------------
__global__ __launch_bounds__(1024)
void compact_kernel(const int* __restrict__ needed,
                    int* __restrict__ list, int* __restrict__ cnt)
{
    __shared__ int s[1024];
    int t = threadIdx.x;
    int nd = 0;
    if (t < NEXPERT) nd = needed[t];
    else if (t < NMAT) nd = 1;             // baselines always needed
    s[t] = nd;
    __syncthreads();
    // Hillis-Steele inclusive scan
    for (int off=1; off<1024; off<<=1){
        int v = (t >= off) ? s[t-off] : 0;
        __syncthreads();
        s[t] += v;
        __syncthreads();
    }
    if (nd) list[s[t]-1] = t;
    if (t == NMAT-1) cnt[0] = s[t];
}

// ---------------------------------------------------------------------------
// Kernel 2: left-looking Cholesky (R5/R7 structure), 512 threads:
// two-thread TEAMS per column. Primary (waves 0-3) builds K + updates
// panels i2 in [0,j/2); secondary (waves 4-7) accumulates i2 in [j/2,j)
// into an LDS partial, combined once per panel. Halves the critical wave's
// update work and doubles waves/CU for latency hiding (we run ~1 block/CU).
// ---------------------------------------------------------------------------
__global__ __launch_bounds__(512)
void chol_kernel(const float* __restrict__ X_exp, const float* __restrict__ Y_exp,
                 const float* __restrict__ X_base, const float* __restrict__ Y_base,
                 const float* __restrict__ lls_e, const float* __restrict__ los_e,
                 const float* __restrict__ lno_e,
                 const float* __restrict__ lls_b, const float* __restrict__ los_b,
                 const float* __restrict__ lno_b,
                 const int* __restrict__ list, const int* __restrict__ cnt,
                 float* __restrict__ Uws, float* __restrict__ Vws)
{
    if (blockIdx.x >= cnt[0]) return;      // early-exit: not needed this run
    int mat = list[blockIdx.x];

    __shared__ __align__(16) float Xs[256*8];    // 8 KB   train points, stride 8
    __shared__ __align__(16) float Bs[7*1024];   // 28 KB  staged B diag-col blocks
    __shared__ __align__(16) float Part[256*36]; // 36 KB  secondary partials
    __shared__ float Dl[32*36];                  // diag block of L
    __shared__ float Dinv[32];                   // 1/diag(L)

    int t = threadIdx.x;
    int w = t >> 6, lane = t & 63;
    bool prim = (t < 256);
    int q = ((w & 3) + blockIdx.x) & 3;          // column chunk (team-matched)
    int c = 64*q + lane;                         // owned column

    const float *Xtr, *Ytr;
    float lls, los, lno;
    if (mat < NEXPERT){
        Xtr = X_exp + mat*(MPTS*DIMS); Ytr = Y_exp + mat*MPTS;
        lls = lls_e[mat]; los = los_e[mat]; lno = lno_e[mat];
    } else {
        int g = mat - NEXPERT;
        Xtr = X_base + g*(MPTS*DIMS); Ytr = Y_base + g*MPTS;
        lls = lls_b[g]; los = los_b[g]; lno = lno_b[g];
    }
    float ls2 = expf(2.f*lls);
    float os  = expf(los);
    float nv  = expf(lno) + JIT;
    float c1  = -0.5f*L2E/ls2;
    float* Ug = Uws + (size_t)mat*USTRIDE;

    // stage X into LDS (padded stride 8; slots 6,7 never read)
    for (int i=t; i<MPTS*DIMS; i+=512){ int r=i/DIMS, d=i-r*DIMS; Xs[r*8+d]=Xtr[i]; }

    for (int j=0; j<8; j++){
        __syncthreads();   // prev panel's Bs/Part reads done + stores drained

        // ---- async-stage B blocks for this panel (all 8 waves) ----
        // Block i2: B[m][k] = U[32*i2+m][32*j+k]; one issue = 64 floats.
        for (int u=w; u<16*j; u+=8){
            int blk = u >> 4, e0 = (u & 15)*64;
            int m  = 2*(u & 15) + (lane >> 5);
            int kk = lane & 31;
            int ri = 32*blk + m;
            const float* gp = Ug + (uoff(ri) + 32*j + kk - ri);
            __builtin_amdgcn_global_load_lds(
                (const __attribute__((address_space(1))) void*)gp,
                (__attribute__((address_space(3))) void*)&Bs[blk*1024 + e0],
                4, 0, 0);
        }

        int l = c - 32*j;                // diag-local index of owned column
        bool act = (l >= 0);
        int jh = j >> 1;                 // primary panels: [0,jh); secondary: [jh,j)
        float x[32];                     // primary: column value; secondary: partial

        // ---- build original K entries (primary; overlaps staging) ----
        if (prim && act){
            float4 xa = *(const float4*)&Xs[c*8];
            float2 xb = *(const float2*)&Xs[c*8+4];
            #pragma unroll
            for (int k=0; k<32; k++){
                const float* Xr = &Xs[(32*j+k)*8];
                float4 ra = *(const float4*)Xr;
                float2 rb = *(const float2*)(Xr+4);
                float d0=xa.x-ra.x, d1=xa.y-ra.y, d2v=xa.z-ra.z, d3=xa.w-ra.w;
                float d4=xb.x-rb.x, d5=xb.y-rb.y;
                float dd = d0*d0+d1*d1+d2v*d2v+d3*d3+d4*d4+d5*d5;
                float val = os*exp2f(c1*dd);
                if (k == l) val += nv;   // diagonal
                x[k] = val;
            }
        } else {
            #pragma unroll
            for (int k=0; k<32; k++) x[k] = 0.f;   // secondary partial
        }
        __syncthreads();   // staging drained (vmcnt 0) -> Bs valid

        // ---- update: team-split over prev panels ----
        if (act){
            int i0 = prim ? 0 : jh;
            int i1 = prim ? jh : j;
            for (int i2=i0; i2<i1; i2++){
                float a[32];
                #pragma unroll
                for (int m=0; m<32; m++){
                    int ri = 32*i2 + m;
                    a[m] = Ug[uoff(ri) + c - ri];     // U[ri][c]
                }
                #pragma unroll 8
                for (int m=0; m<32; m++){
                    const float4* Bp = (const float4*)&Bs[i2*1024 + m*32];
                    float nam = -a[m];
                    #pragma unroll
                    for (int kk=0; kk<8; kk++){
                        float4 bb = Bp[kk];           // broadcast, conflict-free
                        x[kk*4+0] = fmaf(bb.x, nam, x[kk*4+0]);
                        x[kk*4+1] = fmaf(bb.y, nam, x[kk*4+1]);
                        x[kk*4+2] = fmaf(bb.z, nam, x[kk*4+2]);
                        x[kk*4+3] = fmaf(bb.w, nam, x[kk*4+3]);
                    }
                }
            }
            // secondary publishes its (negated) partial
            if (!prim && j > jh){
                float4* Pp = (float4*)&Part[c*36];
                #pragma unroll
                for (int kk=0; kk<8; kk++)
                    Pp[kk] = make_float4(x[kk*4+0], x[kk*4+1], x[kk*4+2], x[kk*4+3]);
            }
        }
        __syncthreads();   // Part ready

        // ---- combine + diag factor + trsm (primary only) ----
        if (prim && act && j > jh){
            const float4* Pp = (const float4*)&Part[c*36];
            #pragma unroll
            for (int kk=0; kk<8; kk++){
                float4 pv = Pp[kk];
                x[kk*4+0] += pv.x; x[kk*4+1] += pv.y;
                x[kk*4+2] += pv.z; x[kk*4+3] += pv.w;
            }
        }

        // ---- diag 32x32 factor: owning primary half-wave, shfl only ----
        if (prim && l >= 0 && l < 32){
            int lb = 32*(j & 1);          // lane base of the diag group
            float r[32];
            #pragma unroll
            for (int k=0; k<32; k++) r[k] = (k <= l) ? x[k] : 0.f;
            float myinv = 1.f;
            #pragma unroll
            for (int cc=0; cc<32; cc++){
                float pivsq = __shfl(r[cc], lb + cc);
                float inv = rsqrtf(pivsq);
                r[cc] *= inv;
                if (l == cc) myinv = inv;
                #pragma unroll
                for (int k=cc+1; k<32; k++) r[k] -= r[cc]*__shfl(r[cc], lb + k);
            }
            Dinv[l] = myinv;
            #pragma unroll
            for (int k=0; k<32; k++){
                if (k <= l) Dl[l*36 + k] = r[k];
                x[k] = r[k];
            }
        }
        __syncthreads();                  // Dl/Dinv visible
        // ---- trsm: in-thread, D via LDS broadcast ----
        if (prim && l >= 32){
            #pragma unroll
            for (int cc=0; cc<32; cc++){
                float a = x[cc]*Dinv[cc];
                x[cc] = a;
                #pragma unroll
                for (int k=cc+1; k<32; k++)
                    x[k] -= Dl[k*36 + cc]*a;
            }
        }
        // ---- store panel column to global (once) ----
        if (prim && act){
            #pragma unroll
            for (int k=0; k<32; k++){
                if (l >= k) Ug[uoff(32*j+k) + l - k] = x[k];
            }
        }
    }
    __syncthreads();

    // v = L^-1 y  (forward solve, wave 0 only; L columns = U rows, coalesced)
    if (t < 64){
        int l = t;
        float z[4], rd[4];
        #pragma unroll
        for (int qq2=0; qq2<4; qq2++){
            z[qq2]  = Ytr[64*qq2 + l];
            rd[qq2] = 1.f/Ug[uoff(64*qq2 + l)];
        }
        int offj = 0;
        #pragma unroll
        for (int qq2=0; qq2<4; qq2++){
            for (int j2=0; j2<64; j2++){
                int j = 64*qq2 + j2;
                float zf = __shfl(z[qq2], j2) * __shfl(rd[qq2], j2);
                if (l == j2) z[qq2] = zf;
                #pragma unroll
                for (int r=qq2; r<4; r++){
                    int dd = 64*(r-qq2) + (l - j2);
                    int dc = dd > 0 ? dd : 0;
                    float uv = Ug[offj + dc];
                    if (dd > 0) z[r] -= uv*zf;
                }
                offj += (259-j)&~3;
            }
        }
        #pragma unroll
        for (int qq2=0; qq2<4; qq2++) Vws[mat*256 + 64*qq2 + l] = z[qq2];
    }
}

// ---------------------------------------------------------------------------
// Kernel 3: per-point prediction (one wave per (point, side)) + rBCM combine.
// Null experts skip the solve (var<-prior => beta_e=0, no poisoned-U reads).
// ---------------------------------------------------------------------------
__global__ __launch_bounds__(256)
void predict_kernel(const float* __restrict__ Xt,
                    const float* __restrict__ X_exp, const float* __restrict__ X_base,
                    const float* __restrict__ lls_e, const float* __restrict__ los_e,
                    const float* __restrict__ lno_e,
                    const float* __restrict__ lls_b, const float* __restrict__ los_b,
                    const float* __restrict__ lno_b,
                    const int* __restrict__ nullmask,
                    const float* __restrict__ Uws, const float* __restrict__ Vws,
                    const int* __restrict__ e_idx, const int* __restrict__ g_idx,
                    float* __restrict__ out)
{
    __shared__ float res[4][4];   // per local wave: mu, var, prior
    int lw = threadIdx.x >> 6, l = threadIdx.x & 63;
    int wt = blockIdx.x*4 + lw, n = wt >> 1, side = wt & 1;

    int bidx; const float* Xtr; float lls, los, lno;
    bool isnull = false;
    if (side == 0){
        int ee = e_idx[n]; bidx = ee; Xtr = X_exp + ee*(MPTS*DIMS);
        lls = lls_e[ee]; los = los_e[ee]; lno = lno_e[ee];
        isnull = (nullmask[ee] == 0);
    } else {
        int g = g_idx[n]; bidx = NEXPERT + g; Xtr = X_base + g*(MPTS*DIMS);
        lls = lls_b[g]; los = los_b[g]; lno = lno_b[g];
    }
    float ls2 = expf(2.f*lls), os = expf(los), nv = expf(lno) + JIT;
    float c1 = -0.5f*L2E/ls2;

    if (!isnull){   // wave-uniform branch
        float xt[DIMS];
        #pragma unroll
        for (int d=0; d<DIMS; d++) xt[d] = Xt[n*DIMS + d];

        const float* Ug = Uws + (size_t)bidx*USTRIDE;
        const float* vv = Vws + bidx*256;

        // k* into registers (rows 64q+l), plus diag reciprocals
        float z[4], rd[4];
        #pragma unroll
        for (int q=0; q<4; q++){
            int m = 64*q + l;
            float d2 = 0.f;
            #pragma unroll
            for (int d=0; d<DIMS; d++){ float df = xt[d]-Xtr[m*DIMS+d]; d2 += df*df; }
            z[q]  = os*exp2f(c1*d2);
            rd[q] = 1.f/Ug[uoff(m)];
        }
        // w = L^-1 k*  (forward solve; L columns = U rows, coalesced loads)
        int offj = 0;
        #pragma unroll
        for (int q=0; q<4; q++){
            #pragma unroll 4
            for (int j2=0; j2<64; j2++){
                int j = 64*q + j2;
                float zf = __shfl(z[q], j2) * __shfl(rd[q], j2);
                if (l == j2) z[q] = zf;
                #pragma unroll
                for (int r=q; r<4; r++){
                    int dd = 64*(r-q) + (l - j2);
                    int dc = dd > 0 ? dd : 0;
                    float uv = Ug[offj + dc];
                    if (dd > 0) z[r] -= uv*zf;
                }
                offj += (259-j)&~3;
            }
        }
        // q = w.w ; mu = w.v
        float qq = 0.f, mu = 0.f;
        #pragma unroll
        for (int q=0; q<4; q++){ qq += z[q]*z[q]; mu += z[q]*vv[64*q + l]; }
        #pragma unroll
        for (int o=32; o>0; o>>=1){ qq += __shfl_xor(qq, o); mu += __shfl_xor(mu, o); }
        if (l == 0){
            res[lw][0] = mu;
            res[lw][1] = fmaxf(os - qq, JIT) + nv;   // predictive var incl noise
            res[lw][2] = os + nv;                    // prior
        }
    } else {
        if (l == 0){
            res[lw][0] = 0.f;
            res[lw][1] = os + nv;    // var = prior -> beta_e = 0, no NaN
            res[lw][2] = os + nv;
        }
    }
    __syncthreads();
    if (threadIdx.x < 2){
        int pp = threadIdx.x, n2 = blockIdx.x*2 + pp;
        float mu_e = res[2*pp][0],   var_e = res[2*pp][1],   pr_e = res[2*pp][2];
        float mu_b = res[2*pp+1][0], var_b = res[2*pp+1][1], pr_b = res[2*pp+1][2];
        int ee = e_idx[n2];
        float be = (nullmask[ee] == 0) ? 0.f
                 : fmaxf(0.5f*(logf(pr_e) - logf(var_e)), 0.f);
        float bb = fmaxf(0.5f*(logf(pr_b) - logf(var_b)), 0.f);
        float prec = be/var_e + bb/var_b + (1.f - be - bb)/pr_b;
        prec = fmaxf(prec, 1e-6f);
        out[n2]        = (be*mu_e/var_e + bb*mu_b/var_b)/prec;
        out[NTEST + n2] = 1.f/prec;
    }
}

// ---------------------------------------------------------------------------
extern "C" void kernel_launch(void* const* d_in, const int* in_sizes, int n_in,
                              void* d_out, int out_size, void* d_ws, size_t ws_size,
                              hipStream_t stream)
{
    const float* X_test  = (const float*)d_in[0];
    const float* X_exp   = (const float*)d_in[1];
    const float* Y_exp   = (const float*)d_in[2];
    const float* X_base  = (const float*)d_in[3];
    const float* Y_base  = (const float*)d_in[4];
    const float* lls_e   = (const float*)d_in[5];
    const float* los_e   = (const float*)d_in[6];
    const float* lno_e   = (const float*)d_in[7];
    const float* lls_b   = (const float*)d_in[8];
    const float* los_b   = (const float*)d_in[9];
    const float* lno_b   = (const float*)d_in[10];
    const float* sm      = (const float*)d_in[11];
    const float* ss      = (const float*)d_in[12];
    const float* gm      = (const float*)d_in[13];
    const float* glv     = (const float*)d_in[14];
    const float* glw     = (const float*)d_in[15];
    const float* pm      = (const float*)d_in[16];
    const float* plv     = (const float*)d_in[17];
    const float* plw     = (const float*)d_in[18];
    const int*   nmask   = (const int*)d_in[19];

    float* Uws = (float*)d_ws;                       // NMAT*USTRIDE floats (74.5 MB)
    float* Vws = Uws + (size_t)NMAT*USTRIDE;         // NMAT*256 floats
    int*   e_idx  = (int*)(Vws + (size_t)NMAT*256);  // NTEST
    int*   g_idx  = e_idx + NTEST;                   // NTEST
    int*   needed = g_idx + NTEST;                   // NMAT
    int*   list   = needed + NMAT;                   // NMAT
    int*   cnt    = list + NMAT;                     // 1
    float* out = (float*)d_out;

    zero_kernel<<<dim3(1), dim3(1024), 0, stream>>>(needed);
    route_kernel<<<dim3(NTEST/256), dim3(256), 0, stream>>>(
        X_test, sm, ss, gm, glv, glw, pm, plv, plw, nmask, e_idx, g_idx, needed);
    compact_kernel<<<dim3(1), dim3(1024), 0, stream>>>(needed, list, cnt);
    chol_kernel<<<dim3(NMAT), dim3(512), 0, stream>>>(
        X_exp, Y_exp, X_base, Y_base,
        lls_e, los_e, lno_e, lls_b, los_b, lno_b, list, cnt, Uws, Vws);
    predict_kernel<<<dim3(NTEST/2), dim3(256), 0, stream>>>(
        X_test, X_exp, X_base,
        lls_e, los_e, lno_e, lls_b, los_b, lno_b,
        nmask, Uws, Vws, e_idx, g_idx, out);
}

// Round 10
// 474.686 us; speedup vs baseline: 3.6842x; 1.0193x over previous
//
#include <hip/hip_runtime.h>
#include <math.h>

// Problem constants
#define DIMS   6
#define NGEO   20
#define NPHI   27
#define NEXPERT 540
#define MPTS   256
#define NTEST  1024
#define NMAT   560          // experts + baselines
#define JIT    1e-4f
#define USTRIDE 33280       // packed padded upper-triangular floats per matrix
#define L2E    1.44269504088896340736f

// Row j of U (cols j..255) starts at uoff(j); each row padded to 4-float multiple.
__device__ __forceinline__ int uoff(int j){
    int m = j >> 2, r = j & 3;
    return 1024*m - 8*m*(m-1) + r*(256 - 4*m);
}

// ---------------------------------------------------------------------------
// Kernel 0: precompute exp(-logvar) and sum(logvar) per GMM cluster in fp64.
// Same exp libcall as before -> bit-identical factors; route then needs no
// transcendentals (was 282 fp64 exp libcalls per point).
// ---------------------------------------------------------------------------
__global__ __launch_bounds__(1024)
void prep_kernel(const float* __restrict__ glv, const float* __restrict__ plv,
                 double* __restrict__ Eg, double* __restrict__ Ep,
                 double* __restrict__ S1g, double* __restrict__ S1p)
{
    int t = threadIdx.x;
    if (t < NGEO*DIMS) Eg[t] = exp(-(double)glv[t]);
    for (int i=t; i<NGEO*NPHI*DIMS; i+=1024) Ep[i] = exp(-(double)plv[i]);
    if (t < NGEO){
        double s = 0.0;
        #pragma unroll
        for (int d=0; d<DIMS; d++) s += (double)glv[t*DIMS+d];
        S1g[t] = s;
    }
    if (t < NGEO*NPHI){
        double s = 0.0;
        #pragma unroll
        for (int d=0; d<DIMS; d++) s += (double)plv[t*DIMS+d];
        S1p[t] = s;
    }
}

// ---------------------------------------------------------------------------
// Kernel 1: 2-level GMM hard routing, fp64 FMA-only (factors precomputed)
// ---------------------------------------------------------------------------
__global__ __launch_bounds__(64)
void route_kernel(const float* __restrict__ Xt, const float* __restrict__ sm,
                  const float* __restrict__ ss,
                  const float* __restrict__ gm, const float* __restrict__ glw,
                  const float* __restrict__ pm, const float* __restrict__ plw,
                  const double* __restrict__ Eg, const double* __restrict__ Ep,
                  const double* __restrict__ S1g, const double* __restrict__ S1p,
                  int* __restrict__ e_idx, int* __restrict__ g_idx)
{
    int n = blockIdx.x*64 + threadIdx.x;
    if (n >= NTEST) return;
    double xs[DIMS];
    #pragma unroll
    for (int d=0; d<DIMS; d++)
        xs[d] = ((double)Xt[n*DIMS+d] - (double)sm[d]) / (double)ss[d];
    const double cst = (double)DIMS * 1.8378770664093453;  // D*log(2*pi)

    int bg = 0; double best = -1e300;
    for (int j=0; j<NGEO; j++){
        double q = 0.0;
        #pragma unroll
        for (int d=0; d<DIMS; d++){
            double df = xs[d] - (double)gm[j*DIMS+d];
            q += df*df*Eg[j*DIMS+d];
        }
        double lp = (double)glw[j] - 0.5*(S1g[j] + q + cst);
        if (lp > best){ best = lp; bg = j; }
    }
    int bk = 0; best = -1e300;
    for (int k=0; k<NPHI; k++){
        double q = 0.0;
        int o = (bg*NPHI + k)*DIMS;
        #pragma unroll
        for (int d=0; d<DIMS; d++){
            double df = xs[d] - (double)pm[o+d];
            q += df*df*Ep[o+d];
        }
        double lp = (double)plw[bg*NPHI+k] - 0.5*(S1p[bg*NPHI+k] + q + cst);
        if (lp > best){ best = lp; bk = k; }
    }
    e_idx[n] = bg*NPHI + bk;
    g_idx[n] = bg;
}

// ---------------------------------------------------------------------------
// Kernel 1b: build needed-flags from e_idx in LDS + compact into worklist
// (single block; absorbs the old zero_kernel and route-side marking)
// ---------------------------------------------------------------------------
__global__ __launch_bounds__(1024)
void compact_kernel(const int* __restrict__ e_idx, const int* __restrict__ nullmask,
                    int* __restrict__ list, int* __restrict__ cnt)
{
    __shared__ int flags[NMAT];
    __shared__ int s[1024];
    int t = threadIdx.x;
    if (t < NEXPERT) flags[t] = 0;
    else if (t < NMAT) flags[t] = 1;       // baselines always needed
    __syncthreads();
    int e = e_idx[t];                      // t in [0,NTEST)
    if (nullmask[e] != 0) flags[e] = 1;    // benign race: same value
    __syncthreads();
    int nd = (t < NMAT) ? flags[t] : 0;
    s[t] = nd;
    __syncthreads();
    // Hillis-Steele inclusive scan
    for (int off=1; off<1024; off<<=1){
        int v = (t >= off) ? s[t-off] : 0;
        __syncthreads();
        s[t] += v;
        __syncthreads();
    }
    if (nd) list[s[t]-1] = t;
    if (t == NMAT-1) cnt[0] = s[t];
}

// ---------------------------------------------------------------------------
// Kernel 2: left-looking Cholesky (R9 structure, frozen at 234 us), 512 thr,
// two-thread teams per column; persistent loop over the worklist (grid 128).
// ---------------------------------------------------------------------------
__global__ __launch_bounds__(512)
void chol_kernel(const float* __restrict__ X_exp, const float* __restrict__ Y_exp,
                 const float* __restrict__ X_base, const float* __restrict__ Y_base,
                 const float* __restrict__ lls_e, const float* __restrict__ los_e,
                 const float* __restrict__ lno_e,
                 const float* __restrict__ lls_b, const float* __restrict__ los_b,
                 const float* __restrict__ lno_b,
                 const int* __restrict__ list, const int* __restrict__ cnt,
                 float* __restrict__ Uws, float* __restrict__ Vws)
{
    __shared__ __align__(16) float Xs[256*8];    // 8 KB   train points, stride 8
    __shared__ __align__(16) float Bs[7*1024];   // 28 KB  staged B diag-col blocks
    __shared__ __align__(16) float Part[256*36]; // 36 KB  secondary partials
    __shared__ float Dl[32*36];                  // diag block of L
    __shared__ float Dinv[32];                   // 1/diag(L)

    int t = threadIdx.x;
    int w = t >> 6, lane = t & 63;
    bool prim = (t < 256);
    int nwork = cnt[0];

    for (int item = blockIdx.x; item < nwork; item += gridDim.x){
    int mat = list[item];
    int q = ((w & 3) + item) & 3;                // column chunk (team-matched)
    int c = 64*q + lane;                         // owned column

    const float *Xtr, *Ytr;
    float lls, los, lno;
    if (mat < NEXPERT){
        Xtr = X_exp + mat*(MPTS*DIMS); Ytr = Y_exp + mat*MPTS;
        lls = lls_e[mat]; los = los_e[mat]; lno = lno_e[mat];
    } else {
        int g = mat - NEXPERT;
        Xtr = X_base + g*(MPTS*DIMS); Ytr = Y_base + g*MPTS;
        lls = lls_b[g]; los = los_b[g]; lno = lno_b[g];
    }
    float ls2 = expf(2.f*lls);
    float os  = expf(los);
    float nv  = expf(lno) + JIT;
    float c1  = -0.5f*L2E/ls2;
    float* Ug = Uws + (size_t)mat*USTRIDE;

    // stage X into LDS (padded stride 8; slots 6,7 never read)
    for (int i=t; i<MPTS*DIMS; i+=512){ int r=i/DIMS, d=i-r*DIMS; Xs[r*8+d]=Xtr[i]; }

    for (int j=0; j<8; j++){
        __syncthreads();   // prev panel's Bs/Part reads done + stores drained

        // ---- async-stage B blocks for this panel (all 8 waves) ----
        for (int u=w; u<16*j; u+=8){
            int blk = u >> 4, e0 = (u & 15)*64;
            int m  = 2*(u & 15) + (lane >> 5);
            int kk = lane & 31;
            int ri = 32*blk + m;
            const float* gp = Ug + (uoff(ri) + 32*j + kk - ri);
            __builtin_amdgcn_global_load_lds(
                (const __attribute__((address_space(1))) void*)gp,
                (__attribute__((address_space(3))) void*)&Bs[blk*1024 + e0],
                4, 0, 0);
        }

        int l = c - 32*j;                // diag-local index of owned column
        bool act = (l >= 0);
        int jh = j >> 1;                 // primary panels: [0,jh); secondary: [jh,j)
        float x[32];                     // primary: column value; secondary: partial

        // ---- build original K entries (primary; overlaps staging) ----
        if (prim && act){
            float4 xa = *(const float4*)&Xs[c*8];
            float2 xb = *(const float2*)&Xs[c*8+4];
            #pragma unroll
            for (int k=0; k<32; k++){
                const float* Xr = &Xs[(32*j+k)*8];
                float4 ra = *(const float4*)Xr;
                float2 rb = *(const float2*)(Xr+4);
                float d0=xa.x-ra.x, d1=xa.y-ra.y, d2v=xa.z-ra.z, d3=xa.w-ra.w;
                float d4=xb.x-rb.x, d5=xb.y-rb.y;
                float dd = d0*d0+d1*d1+d2v*d2v+d3*d3+d4*d4+d5*d5;
                float val = os*exp2f(c1*dd);
                if (k == l) val += nv;   // diagonal
                x[k] = val;
            }
        } else {
            #pragma unroll
            for (int k=0; k<32; k++) x[k] = 0.f;   // secondary partial
        }
        __syncthreads();   // staging drained (vmcnt 0) -> Bs valid

        // ---- update: team-split over prev panels ----
        if (act){
            int i0 = prim ? 0 : jh;
            int i1 = prim ? jh : j;
            for (int i2=i0; i2<i1; i2++){
                float a[32];
                #pragma unroll
                for (int m=0; m<32; m++){
                    int ri = 32*i2 + m;
                    a[m] = Ug[uoff(ri) + c - ri];     // U[ri][c]
                }
                #pragma unroll 8
                for (int m=0; m<32; m++){
                    const float4* Bp = (const float4*)&Bs[i2*1024 + m*32];
                    float nam = -a[m];
                    #pragma unroll
                    for (int kk=0; kk<8; kk++){
                        float4 bb = Bp[kk];           // broadcast, conflict-free
                        x[kk*4+0] = fmaf(bb.x, nam, x[kk*4+0]);
                        x[kk*4+1] = fmaf(bb.y, nam, x[kk*4+1]);
                        x[kk*4+2] = fmaf(bb.z, nam, x[kk*4+2]);
                        x[kk*4+3] = fmaf(bb.w, nam, x[kk*4+3]);
                    }
                }
            }
            // secondary publishes its (negated) partial
            if (!prim && j > jh){
                float4* Pp = (float4*)&Part[c*36];
                #pragma unroll
                for (int kk=0; kk<8; kk++)
                    Pp[kk] = make_float4(x[kk*4+0], x[kk*4+1], x[kk*4+2], x[kk*4+3]);
            }
        }
        __syncthreads();   // Part ready

        // ---- combine (primary only) ----
        if (prim && act && j > jh){
            const float4* Pp = (const float4*)&Part[c*36];
            #pragma unroll
            for (int kk=0; kk<8; kk++){
                float4 pv = Pp[kk];
                x[kk*4+0] += pv.x; x[kk*4+1] += pv.y;
                x[kk*4+2] += pv.z; x[kk*4+3] += pv.w;
            }
        }

        // ---- diag 32x32 factor: owning primary half-wave, shfl only ----
        if (prim && l >= 0 && l < 32){
            int lb = 32*(j & 1);          // lane base of the diag group
            float r[32];
            #pragma unroll
            for (int k=0; k<32; k++) r[k] = (k <= l) ? x[k] : 0.f;
            float myinv = 1.f;
            #pragma unroll
            for (int cc=0; cc<32; cc++){
                float pivsq = __shfl(r[cc], lb + cc);
                float inv = rsqrtf(pivsq);
                r[cc] *= inv;
                if (l == cc) myinv = inv;
                #pragma unroll
                for (int k=cc+1; k<32; k++) r[k] -= r[cc]*__shfl(r[cc], lb + k);
            }
            Dinv[l] = myinv;
            #pragma unroll
            for (int k=0; k<32; k++){
                if (k <= l) Dl[l*36 + k] = r[k];
                x[k] = r[k];
            }
        }
        __syncthreads();                  // Dl/Dinv visible
        // ---- trsm: in-thread, D via LDS broadcast ----
        if (prim && l >= 32){
            #pragma unroll
            for (int cc=0; cc<32; cc++){
                float a = x[cc]*Dinv[cc];
                x[cc] = a;
                #pragma unroll
                for (int k=cc+1; k<32; k++)
                    x[k] -= Dl[k*36 + cc]*a;
            }
        }
        // ---- store panel column to global (once) ----
        if (prim && act){
            #pragma unroll
            for (int k=0; k<32; k++){
                if (l >= k) Ug[uoff(32*j+k) + l - k] = x[k];
            }
        }
    }
    __syncthreads();

    // v = L^-1 y  (forward solve, wave 0 only; L columns = U rows, coalesced)
    if (t < 64){
        int l = t;
        float z[4], rd[4];
        #pragma unroll
        for (int qq2=0; qq2<4; qq2++){
            z[qq2]  = Ytr[64*qq2 + l];
            rd[qq2] = 1.f/Ug[uoff(64*qq2 + l)];
        }
        int offj = 0;
        #pragma unroll
        for (int qq2=0; qq2<4; qq2++){
            for (int j2=0; j2<64; j2++){
                int j = 64*qq2 + j2;
                float zf = __shfl(z[qq2], j2) * __shfl(rd[qq2], j2);
                if (l == j2) z[qq2] = zf;
                #pragma unroll
                for (int r=qq2; r<4; r++){
                    int dd = 64*(r-qq2) + (l - j2);
                    int dc = dd > 0 ? dd : 0;
                    float uv = Ug[offj + dc];
                    if (dd > 0) z[r] -= uv*zf;
                }
                offj += (259-j)&~3;
            }
        }
        #pragma unroll
        for (int qq2=0; qq2<4; qq2++) Vws[mat*256 + 64*qq2 + l] = z[qq2];
    }
    __syncthreads();   // safe LDS reuse for next work item
    }
}

// ---------------------------------------------------------------------------
// Kernel 3: per-point prediction (one wave per (point, side)) + rBCM combine.
// Null experts skip the solve (var<-prior => beta_e=0, no poisoned-U reads).
// ---------------------------------------------------------------------------
__global__ __launch_bounds__(256)
void predict_kernel(const float* __restrict__ Xt,
                    const float* __restrict__ X_exp, const float* __restrict__ X_base,
                    const float* __restrict__ lls_e, const float* __restrict__ los_e,
                    const float* __restrict__ lno_e,
                    const float* __restrict__ lls_b, const float* __restrict__ los_b,
                    const float* __restrict__ lno_b,
                    const int* __restrict__ nullmask,
                    const float* __restrict__ Uws, const float* __restrict__ Vws,
                    const int* __restrict__ e_idx, const int* __restrict__ g_idx,
                    float* __restrict__ out)
{
    __shared__ float res[4][4];   // per local wave: mu, var, prior
    int lw = threadIdx.x >> 6, l = threadIdx.x & 63;
    int wt = blockIdx.x*4 + lw, n = wt >> 1, side = wt & 1;

    int bidx; const float* Xtr; float lls, los, lno;
    bool isnull = false;
    if (side == 0){
        int ee = e_idx[n]; bidx = ee; Xtr = X_exp + ee*(MPTS*DIMS);
        lls = lls_e[ee]; los = los_e[ee]; lno = lno_e[ee];
        isnull = (nullmask[ee] == 0);
    } else {
        int g = g_idx[n]; bidx = NEXPERT + g; Xtr = X_base + g*(MPTS*DIMS);
        lls = lls_b[g]; los = los_b[g]; lno = lno_b[g];
    }
    float ls2 = expf(2.f*lls), os = expf(los), nv = expf(lno) + JIT;
    float c1 = -0.5f*L2E/ls2;

    if (!isnull){   // wave-uniform branch
        float xt[DIMS];
        #pragma unroll
        for (int d=0; d<DIMS; d++) xt[d] = Xt[n*DIMS + d];

        const float* Ug = Uws + (size_t)bidx*USTRIDE;
        const float* vv = Vws + bidx*256;

        // k* into registers (rows 64q+l), plus diag reciprocals
        float z[4], rd[4];
        #pragma unroll
        for (int q=0; q<4; q++){
            int m = 64*q + l;
            float d2 = 0.f;
            #pragma unroll
            for (int d=0; d<DIMS; d++){ float df = xt[d]-Xtr[m*DIMS+d]; d2 += df*df; }
            z[q]  = os*exp2f(c1*d2);
            rd[q] = 1.f/Ug[uoff(m)];
        }
        // w = L^-1 k*  (forward solve; L columns = U rows, coalesced loads)
        int offj = 0;
        #pragma unroll
        for (int q=0; q<4; q++){
            #pragma unroll 4
            for (int j2=0; j2<64; j2++){
                int j = 64*q + j2;
                float zf = __shfl(z[q], j2) * __shfl(rd[q], j2);
                if (l == j2) z[q] = zf;
                #pragma unroll
                for (int r=q; r<4; r++){
                    int dd = 64*(r-q) + (l - j2);
                    int dc = dd > 0 ? dd : 0;
                    float uv = Ug[offj + dc];
                    if (dd > 0) z[r] -= uv*zf;
                }
                offj += (259-j)&~3;
            }
        }
        // q = w.w ; mu = w.v
        float qq = 0.f, mu = 0.f;
        #pragma unroll
        for (int q=0; q<4; q++){ qq += z[q]*z[q]; mu += z[q]*vv[64*q + l]; }
        #pragma unroll
        for (int o=32; o>0; o>>=1){ qq += __shfl_xor(qq, o); mu += __shfl_xor(mu, o); }
        if (l == 0){
            res[lw][0] = mu;
            res[lw][1] = fmaxf(os - qq, JIT) + nv;   // predictive var incl noise
            res[lw][2] = os + nv;                    // prior
        }
    } else {
        if (l == 0){
            res[lw][0] = 0.f;
            res[lw][1] = os + nv;    // var = prior -> beta_e = 0, no NaN
            res[lw][2] = os + nv;
        }
    }
    __syncthreads();
    if (threadIdx.x < 2){
        int pp = threadIdx.x, n2 = blockIdx.x*2 + pp;
        float mu_e = res[2*pp][0],   var_e = res[2*pp][1],   pr_e = res[2*pp][2];
        float mu_b = res[2*pp+1][0], var_b = res[2*pp+1][1], pr_b = res[2*pp+1][2];
        int ee = e_idx[n2];
        float be = (nullmask[ee] == 0) ? 0.f
                 : fmaxf(0.5f*(logf(pr_e) - logf(var_e)), 0.f);
        float bb = fmaxf(0.5f*(logf(pr_b) - logf(var_b)), 0.f);
        float prec = be/var_e + bb/var_b + (1.f - be - bb)/pr_b;
        prec = fmaxf(prec, 1e-6f);
        out[n2]        = (be*mu_e/var_e + bb*mu_b/var_b)/prec;
        out[NTEST + n2] = 1.f/prec;
    }
}

// ---------------------------------------------------------------------------
extern "C" void kernel_launch(void* const* d_in, const int* in_sizes, int n_in,
                              void* d_out, int out_size, void* d_ws, size_t ws_size,
                              hipStream_t stream)
{
    const float* X_test  = (const float*)d_in[0];
    const float* X_exp   = (const float*)d_in[1];
    const float* Y_exp   = (const float*)d_in[2];
    const float* X_base  = (const float*)d_in[3];
    const float* Y_base  = (const float*)d_in[4];
    const float* lls_e   = (const float*)d_in[5];
    const float* los_e   = (const float*)d_in[6];
    const float* lno_e   = (const float*)d_in[7];
    const float* lls_b   = (const float*)d_in[8];
    const float* los_b   = (const float*)d_in[9];
    const float* lno_b   = (const float*)d_in[10];
    const float* sm      = (const float*)d_in[11];
    const float* ss      = (const float*)d_in[12];
    const float* gm      = (const float*)d_in[13];
    const float* glv     = (const float*)d_in[14];
    const float* glw     = (const float*)d_in[15];
    const float* pm      = (const float*)d_in[16];
    const float* plv     = (const float*)d_in[17];
    const float* plw     = (const float*)d_in[18];
    const int*   nmask   = (const int*)d_in[19];

    // ws layout: doubles first (8-aligned), then the big float arrays, then ints
    double* Eg  = (double*)d_ws;                     // 120
    double* Ep  = Eg + NGEO*DIMS;                    // 3240
    double* S1g = Ep + NGEO*NPHI*DIMS;               // 20
    double* S1p = S1g + NGEO;                        // 540
    float* Uws  = (float*)(S1p + NGEO*NPHI);         // NMAT*USTRIDE floats
    float* Vws  = Uws + (size_t)NMAT*USTRIDE;        // NMAT*256 floats
    int*   e_idx = (int*)(Vws + (size_t)NMAT*256);   // NTEST
    int*   g_idx = e_idx + NTEST;                    // NTEST
    int*   list  = g_idx + NTEST;                    // NMAT
    int*   cnt   = list + NMAT;                      // 1
    float* out = (float*)d_out;

    prep_kernel<<<dim3(1), dim3(1024), 0, stream>>>(glv, plv, Eg, Ep, S1g, S1p);
    route_kernel<<<dim3(NTEST/64), dim3(64), 0, stream>>>(
        X_test, sm, ss, gm, glw, pm, plw, Eg, Ep, S1g, S1p, e_idx, g_idx);
    compact_kernel<<<dim3(1), dim3(1024), 0, stream>>>(e_idx, nmask, list, cnt);
    chol_kernel<<<dim3(128), dim3(512), 0, stream>>>(
        X_exp, Y_exp, X_base, Y_base,
        lls_e, los_e, lno_e, lls_b, los_b, lno_b, list, cnt, Uws, Vws);
    predict_kernel<<<dim3(NTEST/2), dim3(256), 0, stream>>>(
        X_test, X_exp, X_base,
        lls_e, los_e, lno_e, lls_b, los_b, lno_b,
        nmask, Uws, Vws, e_idx, g_idx, out);
}

// Round 11
// 402.647 us; speedup vs baseline: 4.3433x; 1.1789x over previous
//
#include <hip/hip_runtime.h>
#include <math.h>

// Problem constants
#define DIMS   6
#define NGEO   20
#define NPHI   27
#define NEXPERT 540
#define MPTS   256
#define NTEST  1024
#define NMAT   560          // experts + baselines
#define JIT    1e-4f
#define USTRIDE 33280       // packed padded upper-triangular floats per matrix
#define L2E    1.44269504088896340736f

// Row j of U (cols j..255) starts at uoff(j); each row padded to 4-float multiple.
__device__ __forceinline__ int uoff(int j){
    int m = j >> 2, r = j & 3;
    return 1024*m - 8*m*(m-1) + r*(256 - 4*m);
}

// ---------------------------------------------------------------------------
// Kernel 0: precompute exp(-logvar) and sum(logvar) per GMM cluster in fp64.
// ---------------------------------------------------------------------------
__global__ __launch_bounds__(1024)
void prep_kernel(const float* __restrict__ glv, const float* __restrict__ plv,
                 double* __restrict__ Eg, double* __restrict__ Ep,
                 double* __restrict__ S1g, double* __restrict__ S1p)
{
    int t = threadIdx.x;
    if (t < NGEO*DIMS) Eg[t] = exp(-(double)glv[t]);
    for (int i=t; i<NGEO*NPHI*DIMS; i+=1024) Ep[i] = exp(-(double)plv[i]);
    if (t < NGEO){
        double s = 0.0;
        #pragma unroll
        for (int d=0; d<DIMS; d++) s += (double)glv[t*DIMS+d];
        S1g[t] = s;
    }
    if (t < NGEO*NPHI){
        double s = 0.0;
        #pragma unroll
        for (int d=0; d<DIMS; d++) s += (double)plv[t*DIMS+d];
        S1p[t] = s;
    }
}

// ---------------------------------------------------------------------------
// Kernel 1: 2-level GMM hard routing, fp64 FMA-only (factors precomputed)
// ---------------------------------------------------------------------------
__global__ __launch_bounds__(64)
void route_kernel(const float* __restrict__ Xt, const float* __restrict__ sm,
                  const float* __restrict__ ss,
                  const float* __restrict__ gm, const float* __restrict__ glw,
                  const float* __restrict__ pm, const float* __restrict__ plw,
                  const double* __restrict__ Eg, const double* __restrict__ Ep,
                  const double* __restrict__ S1g, const double* __restrict__ S1p,
                  int* __restrict__ e_idx, int* __restrict__ g_idx)
{
    int n = blockIdx.x*64 + threadIdx.x;
    if (n >= NTEST) return;
    double xs[DIMS];
    #pragma unroll
    for (int d=0; d<DIMS; d++)
        xs[d] = ((double)Xt[n*DIMS+d] - (double)sm[d]) / (double)ss[d];
    const double cst = (double)DIMS * 1.8378770664093453;  // D*log(2*pi)

    int bg = 0; double best = -1e300;
    for (int j=0; j<NGEO; j++){
        double q = 0.0;
        #pragma unroll
        for (int d=0; d<DIMS; d++){
            double df = xs[d] - (double)gm[j*DIMS+d];
            q += df*df*Eg[j*DIMS+d];
        }
        double lp = (double)glw[j] - 0.5*(S1g[j] + q + cst);
        if (lp > best){ best = lp; bg = j; }
    }
    int bk = 0; best = -1e300;
    for (int k=0; k<NPHI; k++){
        double q = 0.0;
        int o = (bg*NPHI + k)*DIMS;
        #pragma unroll
        for (int d=0; d<DIMS; d++){
            double df = xs[d] - (double)pm[o+d];
            q += df*df*Ep[o+d];
        }
        double lp = (double)plw[bg*NPHI+k] - 0.5*(S1p[bg*NPHI+k] + q + cst);
        if (lp > best){ best = lp; bk = k; }
    }
    e_idx[n] = bg*NPHI + bk;
    g_idx[n] = bg;
}

// ---------------------------------------------------------------------------
// Kernel 1b: build needed-flags from e_idx in LDS + compact into worklist
// ---------------------------------------------------------------------------
__global__ __launch_bounds__(1024)
void compact_kernel(const int* __restrict__ e_idx, const int* __restrict__ nullmask,
                    int* __restrict__ list, int* __restrict__ cnt)
{
    __shared__ int flags[NMAT];
    __shared__ int s[1024];
    int t = threadIdx.x;
    if (t < NEXPERT) flags[t] = 0;
    else if (t < NMAT) flags[t] = 1;       // baselines always needed
    __syncthreads();
    int e = e_idx[t];                      // t in [0,NTEST)
    if (nullmask[e] != 0) flags[e] = 1;    // benign race: same value
    __syncthreads();
    int nd = (t < NMAT) ? flags[t] : 0;
    s[t] = nd;
    __syncthreads();
    // Hillis-Steele inclusive scan
    for (int off=1; off<1024; off<<=1){
        int v = (t >= off) ? s[t-off] : 0;
        __syncthreads();
        s[t] += v;
        __syncthreads();
    }
    if (nd) list[s[t]-1] = t;
    if (t == NMAT-1) cnt[0] = s[t];
}

// ---------------------------------------------------------------------------
// Kernel 2: left-looking Cholesky (frozen R9/R10 structure, 234 us)
// ---------------------------------------------------------------------------
__global__ __launch_bounds__(512)
void chol_kernel(const float* __restrict__ X_exp, const float* __restrict__ Y_exp,
                 const float* __restrict__ X_base, const float* __restrict__ Y_base,
                 const float* __restrict__ lls_e, const float* __restrict__ los_e,
                 const float* __restrict__ lno_e,
                 const float* __restrict__ lls_b, const float* __restrict__ los_b,
                 const float* __restrict__ lno_b,
                 const int* __restrict__ list, const int* __restrict__ cnt,
                 float* __restrict__ Uws, float* __restrict__ Vws)
{
    __shared__ __align__(16) float Xs[256*8];    // 8 KB   train points, stride 8
    __shared__ __align__(16) float Bs[7*1024];   // 28 KB  staged B diag-col blocks
    __shared__ __align__(16) float Part[256*36]; // 36 KB  secondary partials
    __shared__ float Dl[32*36];                  // diag block of L
    __shared__ float Dinv[32];                   // 1/diag(L)

    int t = threadIdx.x;
    int w = t >> 6, lane = t & 63;
    bool prim = (t < 256);
    int nwork = cnt[0];

    for (int item = blockIdx.x; item < nwork; item += gridDim.x){
    int mat = list[item];
    int q = ((w & 3) + item) & 3;                // column chunk (team-matched)
    int c = 64*q + lane;                         // owned column

    const float *Xtr, *Ytr;
    float lls, los, lno;
    if (mat < NEXPERT){
        Xtr = X_exp + mat*(MPTS*DIMS); Ytr = Y_exp + mat*MPTS;
        lls = lls_e[mat]; los = los_e[mat]; lno = lno_e[mat];
    } else {
        int g = mat - NEXPERT;
        Xtr = X_base + g*(MPTS*DIMS); Ytr = Y_base + g*MPTS;
        lls = lls_b[g]; los = los_b[g]; lno = lno_b[g];
    }
    float ls2 = expf(2.f*lls);
    float os  = expf(los);
    float nv  = expf(lno) + JIT;
    float c1  = -0.5f*L2E/ls2;
    float* Ug = Uws + (size_t)mat*USTRIDE;

    // stage X into LDS (padded stride 8; slots 6,7 never read)
    for (int i=t; i<MPTS*DIMS; i+=512){ int r=i/DIMS, d=i-r*DIMS; Xs[r*8+d]=Xtr[i]; }

    for (int j=0; j<8; j++){
        __syncthreads();   // prev panel's Bs/Part reads done + stores drained

        // ---- async-stage B blocks for this panel (all 8 waves) ----
        for (int u=w; u<16*j; u+=8){
            int blk = u >> 4, e0 = (u & 15)*64;
            int m  = 2*(u & 15) + (lane >> 5);
            int kk = lane & 31;
            int ri = 32*blk + m;
            const float* gp = Ug + (uoff(ri) + 32*j + kk - ri);
            __builtin_amdgcn_global_load_lds(
                (const __attribute__((address_space(1))) void*)gp,
                (__attribute__((address_space(3))) void*)&Bs[blk*1024 + e0],
                4, 0, 0);
        }

        int l = c - 32*j;                // diag-local index of owned column
        bool act = (l >= 0);
        int jh = j >> 1;                 // primary panels: [0,jh); secondary: [jh,j)
        float x[32];                     // primary: column value; secondary: partial

        // ---- build original K entries (primary; overlaps staging) ----
        if (prim && act){
            float4 xa = *(const float4*)&Xs[c*8];
            float2 xb = *(const float2*)&Xs[c*8+4];
            #pragma unroll
            for (int k=0; k<32; k++){
                const float* Xr = &Xs[(32*j+k)*8];
                float4 ra = *(const float4*)Xr;
                float2 rb = *(const float2*)(Xr+4);
                float d0=xa.x-ra.x, d1=xa.y-ra.y, d2v=xa.z-ra.z, d3=xa.w-ra.w;
                float d4=xb.x-rb.x, d5=xb.y-rb.y;
                float dd = d0*d0+d1*d1+d2v*d2v+d3*d3+d4*d4+d5*d5;
                float val = os*exp2f(c1*dd);
                if (k == l) val += nv;   // diagonal
                x[k] = val;
            }
        } else {
            #pragma unroll
            for (int k=0; k<32; k++) x[k] = 0.f;   // secondary partial
        }
        __syncthreads();   // staging drained (vmcnt 0) -> Bs valid

        // ---- update: team-split over prev panels ----
        if (act){
            int i0 = prim ? 0 : jh;
            int i1 = prim ? jh : j;
            for (int i2=i0; i2<i1; i2++){
                float a[32];
                #pragma unroll
                for (int m=0; m<32; m++){
                    int ri = 32*i2 + m;
                    a[m] = Ug[uoff(ri) + c - ri];     // U[ri][c]
                }
                #pragma unroll 8
                for (int m=0; m<32; m++){
                    const float4* Bp = (const float4*)&Bs[i2*1024 + m*32];
                    float nam = -a[m];
                    #pragma unroll
                    for (int kk=0; kk<8; kk++){
                        float4 bb = Bp[kk];           // broadcast, conflict-free
                        x[kk*4+0] = fmaf(bb.x, nam, x[kk*4+0]);
                        x[kk*4+1] = fmaf(bb.y, nam, x[kk*4+1]);
                        x[kk*4+2] = fmaf(bb.z, nam, x[kk*4+2]);
                        x[kk*4+3] = fmaf(bb.w, nam, x[kk*4+3]);
                    }
                }
            }
            // secondary publishes its partial
            if (!prim && j > jh){
                float4* Pp = (float4*)&Part[c*36];
                #pragma unroll
                for (int kk=0; kk<8; kk++)
                    Pp[kk] = make_float4(x[kk*4+0], x[kk*4+1], x[kk*4+2], x[kk*4+3]);
            }
        }
        __syncthreads();   // Part ready

        // ---- combine (primary only) ----
        if (prim && act && j > jh){
            const float4* Pp = (const float4*)&Part[c*36];
            #pragma unroll
            for (int kk=0; kk<8; kk++){
                float4 pv = Pp[kk];
                x[kk*4+0] += pv.x; x[kk*4+1] += pv.y;
                x[kk*4+2] += pv.z; x[kk*4+3] += pv.w;
            }
        }

        // ---- diag 32x32 factor: owning primary half-wave, shfl only ----
        if (prim && l >= 0 && l < 32){
            int lb = 32*(j & 1);          // lane base of the diag group
            float r[32];
            #pragma unroll
            for (int k=0; k<32; k++) r[k] = (k <= l) ? x[k] : 0.f;
            float myinv = 1.f;
            #pragma unroll
            for (int cc=0; cc<32; cc++){
                float pivsq = __shfl(r[cc], lb + cc);
                float inv = rsqrtf(pivsq);
                r[cc] *= inv;
                if (l == cc) myinv = inv;
                #pragma unroll
                for (int k=cc+1; k<32; k++) r[k] -= r[cc]*__shfl(r[cc], lb + k);
            }
            Dinv[l] = myinv;
            #pragma unroll
            for (int k=0; k<32; k++){
                if (k <= l) Dl[l*36 + k] = r[k];
                x[k] = r[k];
            }
        }
        __syncthreads();                  // Dl/Dinv visible
        // ---- trsm: in-thread, D via LDS broadcast ----
        if (prim && l >= 32){
            #pragma unroll
            for (int cc=0; cc<32; cc++){
                float a = x[cc]*Dinv[cc];
                x[cc] = a;
                #pragma unroll
                for (int k=cc+1; k<32; k++)
                    x[k] -= Dl[k*36 + cc]*a;
            }
        }
        // ---- store panel column to global (once) ----
        if (prim && act){
            #pragma unroll
            for (int k=0; k<32; k++){
                if (l >= k) Ug[uoff(32*j+k) + l - k] = x[k];
            }
        }
    }
    __syncthreads();

    // v = L^-1 y  (forward solve, wave 0 only; L columns = U rows, coalesced)
    if (t < 64){
        int l = t;
        float z[4], rd[4];
        #pragma unroll
        for (int qq2=0; qq2<4; qq2++){
            z[qq2]  = Ytr[64*qq2 + l];
            rd[qq2] = 1.f/Ug[uoff(64*qq2 + l)];
        }
        int offj = 0;
        #pragma unroll
        for (int qq2=0; qq2<4; qq2++){
            for (int j2=0; j2<64; j2++){
                int j = 64*qq2 + j2;
                float zf = __shfl(z[qq2], j2) * __shfl(rd[qq2], j2);
                if (l == j2) z[qq2] = zf;
                #pragma unroll
                for (int r=qq2; r<4; r++){
                    int dd = 64*(r-qq2) + (l - j2);
                    int dc = dd > 0 ? dd : 0;
                    float uv = Ug[offj + dc];
                    if (dd > 0) z[r] -= uv*zf;
                }
                offj += (259-j)&~3;
            }
        }
        #pragma unroll
        for (int qq2=0; qq2<4; qq2++) Vws[mat*256 + 64*qq2 + l] = z[qq2];
    }
    __syncthreads();   // safe LDS reuse for next work item
    }
}

// ---------------------------------------------------------------------------
// Kernel 3: per-point prediction + rBCM combine. Forward solve with
// 4-COLUMN PIVOT GROUPING: 8 independent shfls per group (pipelined),
// pivots composed in-registers via the 6 intra-group L entries (uniform
// loads, off the dependent chain) -> ~3x shorter shfl chain, bit-identical
// fma ordering to the per-column version.
// ---------------------------------------------------------------------------
__global__ __launch_bounds__(256)
void predict_kernel(const float* __restrict__ Xt,
                    const float* __restrict__ X_exp, const float* __restrict__ X_base,
                    const float* __restrict__ lls_e, const float* __restrict__ los_e,
                    const float* __restrict__ lno_e,
                    const float* __restrict__ lls_b, const float* __restrict__ los_b,
                    const float* __restrict__ lno_b,
                    const int* __restrict__ nullmask,
                    const float* __restrict__ Uws, const float* __restrict__ Vws,
                    const int* __restrict__ e_idx, const int* __restrict__ g_idx,
                    float* __restrict__ out)
{
    __shared__ float res[4][4];   // per local wave: mu, var, prior
    int lw = threadIdx.x >> 6, l = threadIdx.x & 63;
    int wt = blockIdx.x*4 + lw, n = wt >> 1, side = wt & 1;

    int bidx; const float* Xtr; float lls, los, lno;
    bool isnull = false;
    if (side == 0){
        int ee = e_idx[n]; bidx = ee; Xtr = X_exp + ee*(MPTS*DIMS);
        lls = lls_e[ee]; los = los_e[ee]; lno = lno_e[ee];
        isnull = (nullmask[ee] == 0);
    } else {
        int g = g_idx[n]; bidx = NEXPERT + g; Xtr = X_base + g*(MPTS*DIMS);
        lls = lls_b[g]; los = los_b[g]; lno = lno_b[g];
    }
    float ls2 = expf(2.f*lls), os = expf(los), nv = expf(lno) + JIT;
    float c1 = -0.5f*L2E/ls2;

    if (!isnull){   // wave-uniform branch
        float xt[DIMS];
        #pragma unroll
        for (int d=0; d<DIMS; d++) xt[d] = Xt[n*DIMS + d];

        const float* Ug = Uws + (size_t)bidx*USTRIDE;
        const float* vv = Vws + bidx*256;

        // k* into registers (rows 64q+l), plus diag reciprocals
        float z[4], rd[4];
        #pragma unroll
        for (int q=0; q<4; q++){
            int m = 64*q + l;
            float d2 = 0.f;
            #pragma unroll
            for (int d=0; d<DIMS; d++){ float df = xt[d]-Xtr[m*DIMS+d]; d2 += df*df; }
            z[q]  = os*exp2f(c1*d2);
            rd[q] = 1.f/Ug[uoff(m)];
        }
        // w = L^-1 k*  (forward solve, 4-column pivot groups)
        int offj = 0;
        #pragma unroll
        for (int q=0; q<4; q++){
            #pragma unroll 4
            for (int g=0; g<16; g++){
                int j2 = 4*g;
                int jr = 64*q + j2;
                int off0 = offj;
                int off1 = off0 + ((259-jr)&~3);
                int off2 = off1 + ((258-jr)&~3);
                int off3 = off2 + ((257-jr)&~3);
                // raw broadcasts (independent -> pipelined)
                float a0 = __shfl(z[q], j2+0), a1 = __shfl(z[q], j2+1);
                float a2 = __shfl(z[q], j2+2), a3 = __shfl(z[q], j2+3);
                float r0 = __shfl(rd[q], j2+0), r1 = __shfl(rd[q], j2+1);
                float r2 = __shfl(rd[q], j2+2), r3 = __shfl(rd[q], j2+3);
                // intra-group L entries (uniform addresses, off-chain)
                float L10 = Ug[off0+1], L20 = Ug[off0+2], L30 = Ug[off0+3];
                float L21 = Ug[off1+1], L31 = Ug[off1+2];
                float L32 = Ug[off2+1];
                // composed pivots (same fma order as per-column version)
                float zf0 = a0*r0;
                float zf1 = (a1 - L10*zf0)*r1;
                float zf2 = ((a2 - L20*zf0) - L21*zf1)*r2;
                float zf3 = (((a3 - L30*zf0) - L31*zf1) - L32*zf2)*r3;
                if (l == j2+0) z[q] = zf0;
                if (l == j2+1) z[q] = zf1;
                if (l == j2+2) z[q] = zf2;
                if (l == j2+3) z[q] = zf3;
                // bulk update: r == q, lanes strictly below the group
                if (l >= j2+4){
                    z[q] -= Ug[off0 + (l - j2)]*zf0;
                    z[q] -= Ug[off1 + (l - j2 - 1)]*zf1;
                    z[q] -= Ug[off2 + (l - j2 - 2)]*zf2;
                    z[q] -= Ug[off3 + (l - j2 - 3)]*zf3;
                }
                // bulk update: r > q (dd always > 0)
                #pragma unroll
                for (int r=q+1; r<4; r++){
                    int dd = 64*(r-q) + (l - j2);
                    z[r] -= Ug[off0 + dd]*zf0;
                    z[r] -= Ug[off1 + dd - 1]*zf1;
                    z[r] -= Ug[off2 + dd - 2]*zf2;
                    z[r] -= Ug[off3 + dd - 3]*zf3;
                }
                offj = off3 + ((256-jr)&~3);
            }
        }
        // q = w.w ; mu = w.v
        float qq = 0.f, mu = 0.f;
        #pragma unroll
        for (int q=0; q<4; q++){ qq += z[q]*z[q]; mu += z[q]*vv[64*q + l]; }
        #pragma unroll
        for (int o=32; o>0; o>>=1){ qq += __shfl_xor(qq, o); mu += __shfl_xor(mu, o); }
        if (l == 0){
            res[lw][0] = mu;
            res[lw][1] = fmaxf(os - qq, JIT) + nv;   // predictive var incl noise
            res[lw][2] = os + nv;                    // prior
        }
    } else {
        if (l == 0){
            res[lw][0] = 0.f;
            res[lw][1] = os + nv;    // var = prior -> beta_e = 0, no NaN
            res[lw][2] = os + nv;
        }
    }
    __syncthreads();
    if (threadIdx.x < 2){
        int pp = threadIdx.x, n2 = blockIdx.x*2 + pp;
        float mu_e = res[2*pp][0],   var_e = res[2*pp][1],   pr_e = res[2*pp][2];
        float mu_b = res[2*pp+1][0], var_b = res[2*pp+1][1], pr_b = res[2*pp+1][2];
        int ee = e_idx[n2];
        float be = (nullmask[ee] == 0) ? 0.f
                 : fmaxf(0.5f*(logf(pr_e) - logf(var_e)), 0.f);
        float bb = fmaxf(0.5f*(logf(pr_b) - logf(var_b)), 0.f);
        float prec = be/var_e + bb/var_b + (1.f - be - bb)/pr_b;
        prec = fmaxf(prec, 1e-6f);
        out[n2]        = (be*mu_e/var_e + bb*mu_b/var_b)/prec;
        out[NTEST + n2] = 1.f/prec;
    }
}

// ---------------------------------------------------------------------------
extern "C" void kernel_launch(void* const* d_in, const int* in_sizes, int n_in,
                              void* d_out, int out_size, void* d_ws, size_t ws_size,
                              hipStream_t stream)
{
    const float* X_test  = (const float*)d_in[0];
    const float* X_exp   = (const float*)d_in[1];
    const float* Y_exp   = (const float*)d_in[2];
    const float* X_base  = (const float*)d_in[3];
    const float* Y_base  = (const float*)d_in[4];
    const float* lls_e   = (const float*)d_in[5];
    const float* los_e   = (const float*)d_in[6];
    const float* lno_e   = (const float*)d_in[7];
    const float* lls_b   = (const float*)d_in[8];
    const float* los_b   = (const float*)d_in[9];
    const float* lno_b   = (const float*)d_in[10];
    const float* sm      = (const float*)d_in[11];
    const float* ss      = (const float*)d_in[12];
    const float* gm      = (const float*)d_in[13];
    const float* glv     = (const float*)d_in[14];
    const float* glw     = (const float*)d_in[15];
    const float* pm      = (const float*)d_in[16];
    const float* plv     = (const float*)d_in[17];
    const float* plw     = (const float*)d_in[18];
    const int*   nmask   = (const int*)d_in[19];

    // ws layout: doubles first (8-aligned), then the big float arrays, then ints
    double* Eg  = (double*)d_ws;                     // 120
    double* Ep  = Eg + NGEO*DIMS;                    // 3240
    double* S1g = Ep + NGEO*NPHI*DIMS;               // 20
    double* S1p = S1g + NGEO;                        // 540
    float* Uws  = (float*)(S1p + NGEO*NPHI);         // NMAT*USTRIDE floats
    float* Vws  = Uws + (size_t)NMAT*USTRIDE;        // NMAT*256 floats
    int*   e_idx = (int*)(Vws + (size_t)NMAT*256);   // NTEST
    int*   g_idx = e_idx + NTEST;                    // NTEST
    int*   list  = g_idx + NTEST;                    // NMAT
    int*   cnt   = list + NMAT;                      // 1
    float* out = (float*)d_out;

    prep_kernel<<<dim3(1), dim3(1024), 0, stream>>>(glv, plv, Eg, Ep, S1g, S1p);
    route_kernel<<<dim3(NTEST/64), dim3(64), 0, stream>>>(
        X_test, sm, ss, gm, glw, pm, plw, Eg, Ep, S1g, S1p, e_idx, g_idx);
    compact_kernel<<<dim3(1), dim3(1024), 0, stream>>>(e_idx, nmask, list, cnt);
    chol_kernel<<<dim3(128), dim3(512), 0, stream>>>(
        X_exp, Y_exp, X_base, Y_base,
        lls_e, los_e, lno_e, lls_b, los_b, lno_b, list, cnt, Uws, Vws);
    predict_kernel<<<dim3(NTEST/2), dim3(256), 0, stream>>>(
        X_test, X_exp, X_base,
        lls_e, los_e, lno_e, lls_b, los_b, lno_b,
        nmask, Uws, Vws, e_idx, g_idx, out);
}